// Round 2
// baseline (4225.905 us; speedup 1.0000x reference)
//
#include <hip/hip_runtime.h>

// ---------------------------------------------------------------------------
// QLlamaAttention: mixed 4/6/8-bit block fake-quant qlinear (q,k,v,o) + RoPE +
// causal SDPA.  All matmuls use bf16 "split" (hi+lo) MFMA for ~2^-17 relative
// error (needed: attention output is re-quantized; round() flips amplify any
// error by the 4-bit scale step).
//
// Workspace discipline (round-1 crash was OOB past ws_size):
//   uses at most 192 MB of d_ws (+64 MB of d_out as scratch); if
//   ws_size >= 256 MB, a 4th region caches the pre-quantized activations.
// ---------------------------------------------------------------------------

typedef __bf16 bf16_t;
typedef __bf16 bf16x8 __attribute__((ext_vector_type(8)));
typedef float f32x4 __attribute__((ext_vector_type(4)));

#define MFMA16(a, b, c) __builtin_amdgcn_mfma_f32_16x16x32_bf16(a, b, c, 0, 0, 0)

__device__ __forceinline__ void split_bf16(float x, bf16_t& h, bf16_t& l) {
    h = (bf16_t)x;
    l = (bf16_t)(x - (float)h);
}

// ---------------------------------------------------------------------------
// Elementwise mixed block fake-quant (per 32-col block, tiers 4/6/8 bit) of a
// [4096 x N] matrix, optional gather, source either fp32 or split pair.
// One thread per element; amax via shfl over the 32-lane half-wave (quant
// blocks are 32-aligned with lane groups).
// ---------------------------------------------------------------------------
__global__ void quant_split(const float* __restrict__ srcf,
                            const bf16_t* __restrict__ shi, const bf16_t* __restrict__ slo,
                            const int* __restrict__ rid, int src_split, int gather,
                            bf16_t* __restrict__ dhi, bf16_t* __restrict__ dlo) {
    long idx = (long)blockIdx.x * 256 + threadIdx.x;
    int col = (int)(idx & 4095);
    long row = idx >> 12;
    int g = gather ? rid[col] : col;
    long si = row * 4096 + g;
    float v = src_split ? ((float)shi[si] + (float)slo[si]) : srcf[si];
    float a = fabsf(v);
#pragma unroll
    for (int off = 1; off < 32; off <<= 1) a = fmaxf(a, __shfl_xor(a, off, 32));
    float qmax = (col < 2560) ? 7.0f : (col < 3584 ? 31.0f : 127.0f);
    float scale = fmaxf(a / qmax, 1e-8f);
    float q = rintf(v * (1.0f / scale));
    q = fminf(fmaxf(q, -qmax), qmax);
    float dq = q * scale;
    bf16_t h, l;
    split_bf16(dq, h, l);
    dhi[idx] = h;
    dlo[idx] = l;
}

// ---------------------------------------------------------------------------
// GEMM C[4096,4096] = Aq * Bq^T.  128x128 tile, BK=32, 4 waves 2x2, 4x4
// 16x16x32 MFMA per wave, 3 split passes (hh, hl, lh).
//   AQ:   fuse mixed-quant of A during staging (BK==quant block==32)
//   ASPL: A source is a split hi/lo pair (else raw fp32)
//   OSPL: write output as split hi/lo (else fp32)
// ---------------------------------------------------------------------------
template<int AQ, int ASPL, int OSPL>
__global__ __launch_bounds__(256, 2) void gemm_bt(
    const float* __restrict__ Af,
    const bf16_t* __restrict__ AHi, const bf16_t* __restrict__ ALo,
    const int* __restrict__ rid,
    const bf16_t* __restrict__ BHi, const bf16_t* __restrict__ BLo,
    bf16_t* __restrict__ OHi, bf16_t* __restrict__ OLo,
    float* __restrict__ Of) {
    constexpr int K = 4096, N = 4096;
    __shared__ __align__(16) bf16_t sAh[128 * 32];
    __shared__ __align__(16) bf16_t sAl[128 * 32];
    __shared__ __align__(16) bf16_t sBh[128 * 32];
    __shared__ __align__(16) bf16_t sBl[128 * 32];

    const int tid = threadIdx.x;
    const int bx = blockIdx.x & 31, by = blockIdx.x >> 5;
    const int rowBase = by << 7, colBase = bx << 7;
    const int lane = tid & 63, wave = tid >> 6;
    const int wr = (wave >> 1) << 6, wc = (wave & 1) << 6;
    const int n16 = lane & 15, quad = lane >> 4;

    f32x4 acc[4][4];
#pragma unroll
    for (int m = 0; m < 4; ++m)
#pragma unroll
        for (int n = 0; n < 4; ++n) acc[m][n] = (f32x4){0.f, 0.f, 0.f, 0.f};

    for (int k0 = 0; k0 < K; k0 += 32) {
        __syncthreads();
        if (AQ) {
            float qmax = (k0 < 2560) ? 7.0f : (k0 < 3584 ? 31.0f : 127.0f);
#pragma unroll
            for (int i = 0; i < 2; ++i) {
                int l = i * 256 + tid, r = l >> 2, cb = (l & 3) << 3;
                long rowoff = (long)(rowBase + r) * K;
                const int* rp = rid + k0 + cb;
                float v[8];
                float am = 0.f;
#pragma unroll
                for (int j = 0; j < 8; ++j) {
                    int gg = rp[j];
                    float xv = ASPL ? ((float)AHi[rowoff + gg] + (float)ALo[rowoff + gg])
                                    : Af[rowoff + gg];
                    v[j] = xv;
                    am = fmaxf(am, fabsf(xv));
                }
                am = fmaxf(am, __shfl_xor(am, 1, 64));
                am = fmaxf(am, __shfl_xor(am, 2, 64));
                float scale = fmaxf(am / qmax, 1e-8f);
                float inv = 1.0f / scale;
                bf16x8 hv, lv;
#pragma unroll
                for (int j = 0; j < 8; ++j) {
                    float q = rintf(v[j] * inv);
                    q = fminf(fmaxf(q, -qmax), qmax);
                    float dq = q * scale;
                    bf16_t h, l2;
                    split_bf16(dq, h, l2);
                    hv[j] = h;
                    lv[j] = l2;
                }
                *(bf16x8*)&sAh[l << 3] = hv;
                *(bf16x8*)&sAl[l << 3] = lv;
            }
        } else {
#pragma unroll
            for (int i = 0; i < 2; ++i) {
                int l = i * 256 + tid, r = l >> 2, cb = (l & 3) << 3;
                long off = (long)(rowBase + r) * K + k0 + cb;
                *(uint4*)&sAh[l << 3] = *(const uint4*)&AHi[off];
                *(uint4*)&sAl[l << 3] = *(const uint4*)&ALo[off];
            }
        }
#pragma unroll
        for (int i = 0; i < 2; ++i) {
            int l = i * 256 + tid, r = l >> 2, cb = (l & 3) << 3;
            long off = (long)(colBase + r) * K + k0 + cb;
            *(uint4*)&sBh[l << 3] = *(const uint4*)&BHi[off];
            *(uint4*)&sBl[l << 3] = *(const uint4*)&BLo[off];
        }
        __syncthreads();

        bf16x8 ah[4], al[4], bh[4], bl[4];
#pragma unroll
        for (int m = 0; m < 4; ++m) {
            int row = wr + (m << 4) + n16;
            ah[m] = *(const bf16x8*)&sAh[(row << 5) + (quad << 3)];
            al[m] = *(const bf16x8*)&sAl[(row << 5) + (quad << 3)];
        }
#pragma unroll
        for (int n = 0; n < 4; ++n) {
            int row = wc + (n << 4) + n16;
            bh[n] = *(const bf16x8*)&sBh[(row << 5) + (quad << 3)];
            bl[n] = *(const bf16x8*)&sBl[(row << 5) + (quad << 3)];
        }
#pragma unroll
        for (int m = 0; m < 4; ++m)
#pragma unroll
            for (int n = 0; n < 4; ++n) {
                acc[m][n] = MFMA16(ah[m], bh[n], acc[m][n]);
                acc[m][n] = MFMA16(ah[m], bl[n], acc[m][n]);
                acc[m][n] = MFMA16(al[m], bh[n], acc[m][n]);
            }
    }

#pragma unroll
    for (int m = 0; m < 4; ++m)
#pragma unroll
        for (int n = 0; n < 4; ++n) {
            int row = rowBase + wr + (m << 4) + (quad << 2);
            int col = colBase + wc + (n << 4) + n16;
#pragma unroll
            for (int r = 0; r < 4; ++r) {
                if (OSPL) {
                    bf16_t h, l;
                    split_bf16(acc[m][n][r], h, l);
                    OHi[(long)(row + r) * N + col] = h;
                    OLo[(long)(row + r) * N + col] = l;
                } else {
                    Of[(long)(row + r) * N + col] = acc[m][n][r];
                }
            }
        }
}

// ---------------------------------------------------------------------------
// RoPE in place on split q,k.  One block per token; 64 threads compute the
// cos/sin table (double trig of the fp32-rounded angle) into LDS, then all
// threads rotate 32 heads x 64 pairs.
// ---------------------------------------------------------------------------
__global__ void rope2(bf16_t* __restrict__ qh, bf16_t* __restrict__ ql,
                      bf16_t* __restrict__ kh, bf16_t* __restrict__ kl,
                      const int* __restrict__ pos) {
    int t = blockIdx.x;
    int tid = threadIdx.x;
    __shared__ float cs[64], sn[64];
    if (tid < 64) {
        float invf = (float)pow(10000.0, -(double)tid / 64.0);
        float ang = (float)pos[t] * invf;     // fp32 product, like the reference
        cs[tid] = (float)cos((double)ang);
        sn[tid] = (float)sin((double)ang);
    }
    __syncthreads();
#pragma unroll
    for (int i = 0; i < 8; ++i) {
        int l = i * 256 + tid;
        int hh = l >> 6, d = l & 63;
        long base = (long)t * 4096 + hh * 128 + d;
        float c = cs[d], s = sn[d];
        float a0 = (float)qh[base] + (float)ql[base];
        float a1 = (float)qh[base + 64] + (float)ql[base + 64];
        float r0 = a0 * c - a1 * s, r1 = a1 * c + a0 * s;
        bf16_t x, y;
        split_bf16(r0, x, y); qh[base] = x;      ql[base] = y;
        split_bf16(r1, x, y); qh[base + 64] = x; ql[base + 64] = y;
        float b0 = (float)kh[base] + (float)kl[base];
        float b1 = (float)kh[base + 64] + (float)kl[base + 64];
        r0 = b0 * c - b1 * s; r1 = b1 * c + b0 * s;
        split_bf16(r0, x, y); kh[base] = x;      kl[base] = y;
        split_bf16(r1, x, y); kh[base + 64] = x; kl[base + 64] = y;
    }
}

// ---------------------------------------------------------------------------
// Transpose split V [tok, h*128+d] -> vT[(b*32+h)*128+d][s], both planes.
// ---------------------------------------------------------------------------
__global__ void transpose_vt(const ushort* __restrict__ vh, const ushort* __restrict__ vl,
                             ushort* __restrict__ th, ushort* __restrict__ tl) {
    __shared__ ushort t0[64][68];
    __shared__ ushort t1[64][68];
    int ct = blockIdx.x, tt = blockIdx.y, tid = threadIdx.x;
#pragma unroll
    for (int i = 0; i < 16; ++i) {
        int l = i * 256 + tid, r = l >> 6, c = l & 63;
        long idx = (long)(tt * 64 + r) * 4096 + ct * 64 + c;
        t0[r][c] = vh[idx];
        t1[r][c] = vl[idx];
    }
    __syncthreads();
#pragma unroll
    for (int i = 0; i < 16; ++i) {
        int l = i * 256 + tid, dr = l >> 6, sc = l & 63;
        int colg = ct * 64 + dr, hh = colg >> 7, dl = colg & 127;
        int tok = tt * 64 + sc, b = tok >> 11, s = tok & 2047;
        long o = (long)((b * 32 + hh) * 128 + dl) * 2048 + s;
        th[o] = t0[sc][dr];
        tl[o] = t1[sc][dr];
    }
}

// ---------------------------------------------------------------------------
// Causal flash attention.  Block = 64 q rows (4 waves x 16); q,k read directly
// as split bf16 fragments (zero conversion); 4-term split MFMA in both QK^T
// and PV; P transposed through padded LDS; output written split.
// ---------------------------------------------------------------------------
__global__ __launch_bounds__(256, 2) void flash_attn(
    const bf16_t* __restrict__ qhp, const bf16_t* __restrict__ qlp,
    const bf16_t* __restrict__ khp, const bf16_t* __restrict__ klp,
    const bf16_t* __restrict__ vth, const bf16_t* __restrict__ vtl,
    bf16_t* __restrict__ ohi, bf16_t* __restrict__ olo) {
    __shared__ float pls[4][16][68];
    const int qb = blockIdx.x;          // 0..31
    const int bh = blockIdx.y;          // 0..63
    const int b = bh >> 5, h = bh & 31;
    const int tid = threadIdx.x;
    const int wave = tid >> 6, lane = tid & 63;
    const int n16 = lane & 15, quad = lane >> 4;
    const int q0 = qb * 64 + wave * 16;
    const long tokQ = (long)b * 2048 + q0;
    const float scale = 0.08838834764831845f;   // 1/sqrt(128)

    bf16x8 qhi[4], qlo[4];
    {
        long qoff = (tokQ + n16) * 4096 + h * 128 + quad * 8;
#pragma unroll
        for (int f = 0; f < 4; ++f) {
            qhi[f] = *(const bf16x8*)&qhp[qoff + f * 32];
            qlo[f] = *(const bf16x8*)&qlp[qoff + f * 32];
        }
    }

    f32x4 o[8];
#pragma unroll
    for (int dc = 0; dc < 8; ++dc) o[dc] = (f32x4){0.f, 0.f, 0.f, 0.f};
    float m_i[4] = {-1e30f, -1e30f, -1e30f, -1e30f};
    float l_i[4] = {0.f, 0.f, 0.f, 0.f};

    for (int kb = 0; kb <= qb; ++kb) {
        const long keyTok = (long)b * 2048 + kb * 64;
        f32x4 s[4];
#pragma unroll
        for (int nt = 0; nt < 4; ++nt) {
            f32x4 sc = (f32x4){0.f, 0.f, 0.f, 0.f};
            long koff = (keyTok + nt * 16 + n16) * 4096 + h * 128 + quad * 8;
#pragma unroll
            for (int f = 0; f < 4; ++f) {
                bf16x8 kh = *(const bf16x8*)&khp[koff + f * 32];
                bf16x8 kl = *(const bf16x8*)&klp[koff + f * 32];
                sc = MFMA16(qhi[f], kh, sc);
                sc = MFMA16(qhi[f], kl, sc);
                sc = MFMA16(qlo[f], kh, sc);
                sc = MFMA16(qlo[f], kl, sc);
            }
            int key = kb * 64 + nt * 16 + n16;
#pragma unroll
            for (int r = 0; r < 4; ++r) {
                int qrow = q0 + quad * 4 + r;
                s[nt][r] = (key <= qrow) ? sc[r] * scale : -1e30f;
            }
        }
        float mnew[4], alpha[4];
#pragma unroll
        for (int r = 0; r < 4; ++r) {
            float mx = fmaxf(fmaxf(s[0][r], s[1][r]), fmaxf(s[2][r], s[3][r]));
#pragma unroll
            for (int off = 1; off < 16; off <<= 1) mx = fmaxf(mx, __shfl_xor(mx, off, 64));
            mnew[r] = fmaxf(m_i[r], mx);
            alpha[r] = expf(m_i[r] - mnew[r]);
            m_i[r] = mnew[r];
        }
#pragma unroll
        for (int r = 0; r < 4; ++r) {
            float sum = 0.f;
#pragma unroll
            for (int nt = 0; nt < 4; ++nt) {
                float p = expf(s[nt][r] - mnew[r]);
                s[nt][r] = p;
                sum += p;
            }
#pragma unroll
            for (int off = 1; off < 16; off <<= 1) sum += __shfl_xor(sum, off, 64);
            l_i[r] = l_i[r] * alpha[r] + sum;
        }
#pragma unroll
        for (int nt = 0; nt < 4; ++nt)
#pragma unroll
            for (int r = 0; r < 4; ++r)
                pls[wave][quad * 4 + r][nt * 16 + n16] = s[nt][r];
        __syncthreads();
        bf16x8 phi[2], plo2[2];
#pragma unroll
        for (int kf = 0; kf < 2; ++kf) {
            const float* pp = &pls[wave][n16][kf * 32 + quad * 8];
            bf16x8 hv, lv;
#pragma unroll
            for (int j = 0; j < 8; ++j) {
                bf16_t hh2, ll2;
                split_bf16(pp[j], hh2, ll2);
                hv[j] = hh2;
                lv[j] = ll2;
            }
            phi[kf] = hv;
            plo2[kf] = lv;
        }
#pragma unroll
        for (int dc = 0; dc < 8; ++dc)
#pragma unroll
            for (int r = 0; r < 4; ++r) o[dc][r] *= alpha[r];
#pragma unroll
        for (int dc = 0; dc < 8; ++dc) {
            long vrow = (long)(bh * 128 + dc * 16 + n16) * 2048 + kb * 64 + quad * 8;
#pragma unroll
            for (int kf = 0; kf < 2; ++kf) {
                bf16x8 vh = *(const bf16x8*)(vth + vrow + kf * 32);
                bf16x8 vl = *(const bf16x8*)(vtl + vrow + kf * 32);
                o[dc] = MFMA16(phi[kf], vh, o[dc]);
                o[dc] = MFMA16(phi[kf], vl, o[dc]);
                o[dc] = MFMA16(plo2[kf], vh, o[dc]);
                o[dc] = MFMA16(plo2[kf], vl, o[dc]);
            }
        }
        __syncthreads();
    }
#pragma unroll
    for (int r = 0; r < 4; ++r) {
        float invl = 1.0f / l_i[r];
        long row = tokQ + quad * 4 + r;
#pragma unroll
        for (int dc = 0; dc < 8; ++dc) {
            bf16_t hh2, ll2;
            split_bf16(o[dc][r] * invl, hh2, ll2);
            ohi[row * 4096 + h * 128 + dc * 16 + n16] = hh2;
            olo[row * 4096 + h * 128 + dc * 16 + n16] = ll2;
        }
    }
}

// ---------------------------------------------------------------------------
// Launcher.  ws regions (64 MB each): W0 [0,64) weights-split / vT,
// W1 [64,128) q-split / Wo-split, W2 [128,192) k-split / final fp32,
// OUT = d_out used as v-split then attn-split scratch.  W3 [192,256) only if
// ws_size >= 256 MB (pre-quantized activation cache).
// ---------------------------------------------------------------------------
extern "C" void kernel_launch(void* const* d_in, const int* in_sizes, int n_in,
                              void* d_out, int out_size, void* d_ws, size_t ws_size,
                              hipStream_t stream) {
    const float* x  = (const float*)d_in[0];
    const float* Wq = (const float*)d_in[1];
    const float* Wk = (const float*)d_in[2];
    const float* Wv = (const float*)d_in[3];
    const float* Wo = (const float*)d_in[4];
    const int* pos  = (const int*)d_in[5];
    const int* rid  = (const int*)d_in[6];

    const size_t MB = 1024ull * 1024ull;
    char* ws = (char*)d_ws;
    bf16_t* W0h = (bf16_t*)(ws);
    bf16_t* W0l = (bf16_t*)(ws + 32 * MB);
    bf16_t* W1h = (bf16_t*)(ws + 64 * MB);
    bf16_t* W1l = (bf16_t*)(ws + 96 * MB);
    bf16_t* W2h = (bf16_t*)(ws + 128 * MB);
    bf16_t* W2l = (bf16_t*)(ws + 160 * MB);
    bf16_t* OUh = (bf16_t*)d_out;
    bf16_t* OUl = (bf16_t*)((char*)d_out + 32 * MB);
    bf16_t* W3h = (bf16_t*)(ws + 192 * MB);
    bf16_t* W3l = (bf16_t*)(ws + 224 * MB);
    const bool fast = (ws_size >= 256 * MB);

    const int QG = 65536;   // 16.8M / 256

    // ---- q = xq @ Wq^T ----
    quant_split<<<QG, 256, 0, stream>>>(Wq, nullptr, nullptr, rid, 0, 0, W0h, W0l);
    if (fast) {
        quant_split<<<QG, 256, 0, stream>>>(x, nullptr, nullptr, rid, 0, 1, W3h, W3l);
        gemm_bt<0, 1, 1><<<1024, 256, 0, stream>>>(nullptr, W3h, W3l, rid, W0h, W0l, W1h, W1l, nullptr);
    } else {
        gemm_bt<1, 0, 1><<<1024, 256, 0, stream>>>(x, nullptr, nullptr, rid, W0h, W0l, W1h, W1l, nullptr);
    }
    // ---- k ----
    quant_split<<<QG, 256, 0, stream>>>(Wk, nullptr, nullptr, rid, 0, 0, W0h, W0l);
    if (fast)
        gemm_bt<0, 1, 1><<<1024, 256, 0, stream>>>(nullptr, W3h, W3l, rid, W0h, W0l, W2h, W2l, nullptr);
    else
        gemm_bt<1, 0, 1><<<1024, 256, 0, stream>>>(x, nullptr, nullptr, rid, W0h, W0l, W2h, W2l, nullptr);
    // ---- v (into d_out scratch) ----
    quant_split<<<QG, 256, 0, stream>>>(Wv, nullptr, nullptr, rid, 0, 0, W0h, W0l);
    if (fast)
        gemm_bt<0, 1, 1><<<1024, 256, 0, stream>>>(nullptr, W3h, W3l, rid, W0h, W0l, OUh, OUl, nullptr);
    else
        gemm_bt<1, 0, 1><<<1024, 256, 0, stream>>>(x, nullptr, nullptr, rid, W0h, W0l, OUh, OUl, nullptr);

    rope2<<<4096, 256, 0, stream>>>(W1h, W1l, W2h, W2l, pos);

    transpose_vt<<<dim3(64, 64), 256, 0, stream>>>((const ushort*)OUh, (const ushort*)OUl,
                                                   (ushort*)W0h, (ushort*)W0l);

    flash_attn<<<dim3(32, 64), 256, 0, stream>>>(W1h, W1l, W2h, W2l, W0h, W0l, OUh, OUl);

    // ---- out = attnq @ Wo^T ----
    quant_split<<<QG, 256, 0, stream>>>(Wo, nullptr, nullptr, rid, 0, 0, W1h, W1l);
    float* outf = (float*)W2h;   // k-split dead
    if (fast) {
        quant_split<<<QG, 256, 0, stream>>>(nullptr, OUh, OUl, rid, 1, 1, W3h, W3l);
        gemm_bt<0, 1, 0><<<1024, 256, 0, stream>>>(nullptr, W3h, W3l, rid, W1h, W1l, nullptr, nullptr, outf);
    } else {
        gemm_bt<1, 1, 0><<<1024, 256, 0, stream>>>(nullptr, OUh, OUl, rid, W1h, W1l, nullptr, nullptr, outf);
    }
    hipMemcpyAsync(d_out, outf, 64 * MB, hipMemcpyDeviceToDevice, stream);

    (void)in_sizes; (void)n_in; (void)out_size;
}

// Round 3
// 2984.704 us; speedup vs baseline: 1.4159x; 1.4159x over previous
//
#include <hip/hip_runtime.h>

// ---------------------------------------------------------------------------
// QLlamaAttention: mixed 4/6/8-bit block fake-quant qlinear (q,k,v,o) + RoPE +
// causal SDPA.  All matmuls use bf16 "split" (hi+lo) MFMA for ~2^-17 relative
// error (needed: attention output is re-quantized; round() flips amplify any
// error by the 4-bit scale step).
//
// R2 -> R3: flash_attn rebuilt as LDS-staged 128-row-q-tile kernel (was
// latency-bound at 5.5% MfmaUtil loading K/V fragments straight from global).
// ---------------------------------------------------------------------------

typedef __bf16 bf16_t;
typedef __bf16 bf16x8 __attribute__((ext_vector_type(8)));
typedef float f32x4 __attribute__((ext_vector_type(4)));

#define MFMA16(a, b, c) __builtin_amdgcn_mfma_f32_16x16x32_bf16(a, b, c, 0, 0, 0)

__device__ __forceinline__ void split_bf16(float x, bf16_t& h, bf16_t& l) {
    h = (bf16_t)x;
    l = (bf16_t)(x - (float)h);
}

// ---------------------------------------------------------------------------
// Elementwise mixed block fake-quant of a [4096 x 4096] matrix.
// ---------------------------------------------------------------------------
__global__ void quant_split(const float* __restrict__ srcf,
                            const bf16_t* __restrict__ shi, const bf16_t* __restrict__ slo,
                            const int* __restrict__ rid, int src_split, int gather,
                            bf16_t* __restrict__ dhi, bf16_t* __restrict__ dlo) {
    long idx = (long)blockIdx.x * 256 + threadIdx.x;
    int col = (int)(idx & 4095);
    long row = idx >> 12;
    int g = gather ? rid[col] : col;
    long si = row * 4096 + g;
    float v = src_split ? ((float)shi[si] + (float)slo[si]) : srcf[si];
    float a = fabsf(v);
#pragma unroll
    for (int off = 1; off < 32; off <<= 1) a = fmaxf(a, __shfl_xor(a, off, 32));
    float qmax = (col < 2560) ? 7.0f : (col < 3584 ? 31.0f : 127.0f);
    float scale = fmaxf(a / qmax, 1e-8f);
    float q = rintf(v * (1.0f / scale));
    q = fminf(fmaxf(q, -qmax), qmax);
    float dq = q * scale;
    bf16_t h, l;
    split_bf16(dq, h, l);
    dhi[idx] = h;
    dlo[idx] = l;
}

// ---------------------------------------------------------------------------
// GEMM C[4096,4096] = Aq * Bq^T.  128x128 tile, BK=32, 3 split passes.
// ---------------------------------------------------------------------------
template<int AQ, int ASPL, int OSPL>
__global__ __launch_bounds__(256, 2) void gemm_bt(
    const float* __restrict__ Af,
    const bf16_t* __restrict__ AHi, const bf16_t* __restrict__ ALo,
    const int* __restrict__ rid,
    const bf16_t* __restrict__ BHi, const bf16_t* __restrict__ BLo,
    bf16_t* __restrict__ OHi, bf16_t* __restrict__ OLo,
    float* __restrict__ Of) {
    constexpr int K = 4096, N = 4096;
    __shared__ __align__(16) bf16_t sAh[128 * 32];
    __shared__ __align__(16) bf16_t sAl[128 * 32];
    __shared__ __align__(16) bf16_t sBh[128 * 32];
    __shared__ __align__(16) bf16_t sBl[128 * 32];

    const int tid = threadIdx.x;
    const int bx = blockIdx.x & 31, by = blockIdx.x >> 5;
    const int rowBase = by << 7, colBase = bx << 7;
    const int lane = tid & 63, wave = tid >> 6;
    const int wr = (wave >> 1) << 6, wc = (wave & 1) << 6;
    const int n16 = lane & 15, quad = lane >> 4;

    f32x4 acc[4][4];
#pragma unroll
    for (int m = 0; m < 4; ++m)
#pragma unroll
        for (int n = 0; n < 4; ++n) acc[m][n] = (f32x4){0.f, 0.f, 0.f, 0.f};

    for (int k0 = 0; k0 < K; k0 += 32) {
        __syncthreads();
        if (AQ) {
            float qmax = (k0 < 2560) ? 7.0f : (k0 < 3584 ? 31.0f : 127.0f);
#pragma unroll
            for (int i = 0; i < 2; ++i) {
                int l = i * 256 + tid, r = l >> 2, cb = (l & 3) << 3;
                long rowoff = (long)(rowBase + r) * K;
                const int* rp = rid + k0 + cb;
                float v[8];
                float am = 0.f;
#pragma unroll
                for (int j = 0; j < 8; ++j) {
                    int gg = rp[j];
                    float xv = ASPL ? ((float)AHi[rowoff + gg] + (float)ALo[rowoff + gg])
                                    : Af[rowoff + gg];
                    v[j] = xv;
                    am = fmaxf(am, fabsf(xv));
                }
                am = fmaxf(am, __shfl_xor(am, 1, 64));
                am = fmaxf(am, __shfl_xor(am, 2, 64));
                float scale = fmaxf(am / qmax, 1e-8f);
                float inv = 1.0f / scale;
                bf16x8 hv, lv;
#pragma unroll
                for (int j = 0; j < 8; ++j) {
                    float q = rintf(v[j] * inv);
                    q = fminf(fmaxf(q, -qmax), qmax);
                    float dq = q * scale;
                    bf16_t h, l2;
                    split_bf16(dq, h, l2);
                    hv[j] = h;
                    lv[j] = l2;
                }
                *(bf16x8*)&sAh[l << 3] = hv;
                *(bf16x8*)&sAl[l << 3] = lv;
            }
        } else {
#pragma unroll
            for (int i = 0; i < 2; ++i) {
                int l = i * 256 + tid, r = l >> 2, cb = (l & 3) << 3;
                long off = (long)(rowBase + r) * K + k0 + cb;
                *(uint4*)&sAh[l << 3] = *(const uint4*)&AHi[off];
                *(uint4*)&sAl[l << 3] = *(const uint4*)&ALo[off];
            }
        }
#pragma unroll
        for (int i = 0; i < 2; ++i) {
            int l = i * 256 + tid, r = l >> 2, cb = (l & 3) << 3;
            long off = (long)(colBase + r) * K + k0 + cb;
            *(uint4*)&sBh[l << 3] = *(const uint4*)&BHi[off];
            *(uint4*)&sBl[l << 3] = *(const uint4*)&BLo[off];
        }
        __syncthreads();

        bf16x8 ah[4], al[4], bh[4], bl[4];
#pragma unroll
        for (int m = 0; m < 4; ++m) {
            int row = wr + (m << 4) + n16;
            ah[m] = *(const bf16x8*)&sAh[(row << 5) + (quad << 3)];
            al[m] = *(const bf16x8*)&sAl[(row << 5) + (quad << 3)];
        }
#pragma unroll
        for (int n = 0; n < 4; ++n) {
            int row = wc + (n << 4) + n16;
            bh[n] = *(const bf16x8*)&sBh[(row << 5) + (quad << 3)];
            bl[n] = *(const bf16x8*)&sBl[(row << 5) + (quad << 3)];
        }
#pragma unroll
        for (int m = 0; m < 4; ++m)
#pragma unroll
            for (int n = 0; n < 4; ++n) {
                acc[m][n] = MFMA16(ah[m], bh[n], acc[m][n]);
                acc[m][n] = MFMA16(ah[m], bl[n], acc[m][n]);
                acc[m][n] = MFMA16(al[m], bh[n], acc[m][n]);
            }
    }

#pragma unroll
    for (int m = 0; m < 4; ++m)
#pragma unroll
        for (int n = 0; n < 4; ++n) {
            int row = rowBase + wr + (m << 4) + (quad << 2);
            int col = colBase + wc + (n << 4) + n16;
#pragma unroll
            for (int r = 0; r < 4; ++r) {
                if (OSPL) {
                    bf16_t h, l;
                    split_bf16(acc[m][n][r], h, l);
                    OHi[(long)(row + r) * N + col] = h;
                    OLo[(long)(row + r) * N + col] = l;
                } else {
                    Of[(long)(row + r) * N + col] = acc[m][n][r];
                }
            }
        }
}

// ---------------------------------------------------------------------------
// RoPE in place on split q,k.
// ---------------------------------------------------------------------------
__global__ void rope2(bf16_t* __restrict__ qh, bf16_t* __restrict__ ql,
                      bf16_t* __restrict__ kh, bf16_t* __restrict__ kl,
                      const int* __restrict__ pos) {
    int t = blockIdx.x;
    int tid = threadIdx.x;
    __shared__ float cs[64], sn[64];
    if (tid < 64) {
        float invf = (float)pow(10000.0, -(double)tid / 64.0);
        float ang = (float)pos[t] * invf;
        cs[tid] = (float)cos((double)ang);
        sn[tid] = (float)sin((double)ang);
    }
    __syncthreads();
#pragma unroll
    for (int i = 0; i < 8; ++i) {
        int l = i * 256 + tid;
        int hh = l >> 6, d = l & 63;
        long base = (long)t * 4096 + hh * 128 + d;
        float c = cs[d], s = sn[d];
        float a0 = (float)qh[base] + (float)ql[base];
        float a1 = (float)qh[base + 64] + (float)ql[base + 64];
        float r0 = a0 * c - a1 * s, r1 = a1 * c + a0 * s;
        bf16_t x, y;
        split_bf16(r0, x, y); qh[base] = x;      ql[base] = y;
        split_bf16(r1, x, y); qh[base + 64] = x; ql[base + 64] = y;
        float b0 = (float)kh[base] + (float)kl[base];
        float b1 = (float)kh[base + 64] + (float)kl[base + 64];
        r0 = b0 * c - b1 * s; r1 = b1 * c + b0 * s;
        split_bf16(r0, x, y); kh[base] = x;      kl[base] = y;
        split_bf16(r1, x, y); kh[base + 64] = x; kl[base + 64] = y;
    }
}

// ---------------------------------------------------------------------------
// Transpose split V [tok, h*128+d] -> vT[(b*32+h)*128+d][s], both planes.
// ---------------------------------------------------------------------------
__global__ void transpose_vt(const ushort* __restrict__ vh, const ushort* __restrict__ vl,
                             ushort* __restrict__ th, ushort* __restrict__ tl) {
    __shared__ ushort t0[64][68];
    __shared__ ushort t1[64][68];
    int ct = blockIdx.x, tt = blockIdx.y, tid = threadIdx.x;
#pragma unroll
    for (int i = 0; i < 16; ++i) {
        int l = i * 256 + tid, r = l >> 6, c = l & 63;
        long idx = (long)(tt * 64 + r) * 4096 + ct * 64 + c;
        t0[r][c] = vh[idx];
        t1[r][c] = vl[idx];
    }
    __syncthreads();
#pragma unroll
    for (int i = 0; i < 16; ++i) {
        int l = i * 256 + tid, dr = l >> 6, sc = l & 63;
        int colg = ct * 64 + dr, hh = colg >> 7, dl = colg & 127;
        int tok = tt * 64 + sc, b = tok >> 11, s = tok & 2047;
        long o = (long)((b * 32 + hh) * 128 + dl) * 2048 + s;
        th[o] = t0[sc][dr];
        tl[o] = t1[sc][dr];
    }
}

// ---------------------------------------------------------------------------
// Causal flash attention, LDS-staged.
// Grid (16 q-tiles, 64 b*h).  Block = 256 threads = 4 waves; wave w owns
// 32 q rows (2 m-frags of 16).  Per kb step: cooperatively stage the 64-key
// K tile (64x128, hi+lo) and V^T tile (128x64, hi+lo) into LDS with coalesced
// 16B loads; QK^T and PV use 3-pass split MFMA on LDS-resident fragments.
// P transposes through per-wave LDS slots aliased into the K region
// (guarded by an extra barrier).  LDS 70 KB -> 2 blocks/CU.
// ---------------------------------------------------------------------------
__global__ __launch_bounds__(256, 2) void flash_attn2(
    const bf16_t* __restrict__ qhp, const bf16_t* __restrict__ qlp,
    const bf16_t* __restrict__ khp, const bf16_t* __restrict__ klp,
    const bf16_t* __restrict__ vth, const bf16_t* __restrict__ vtl,
    bf16_t* __restrict__ ohi, bf16_t* __restrict__ olo) {
    __shared__ __align__(16) char smem[71680];
    bf16_t (*sKh)[136] = (bf16_t (*)[136])(smem);            // 64x136x2 = 17408
    bf16_t (*sKl)[136] = (bf16_t (*)[136])(smem + 17408);
    bf16_t (*sVh)[72]  = (bf16_t (*)[72]) (smem + 34816);    // 128x72x2 = 18432
    bf16_t (*sVl)[72]  = (bf16_t (*)[72]) (smem + 53248);

    const int qt = blockIdx.x;          // 0..15
    const int bh = blockIdx.y;          // 0..63
    const int b = bh >> 5, h = bh & 31;
    const int tid = threadIdx.x;
    const int wave = tid >> 6, lane = tid & 63;
    const int n16 = lane & 15, quad = lane >> 4;
    const long tokB = (long)b * 2048;
    const int q0 = qt * 128 + wave * 32;   // wave's first q row (2 frags of 16)
    const float scale = 0.08838834764831845f;   // 1/sqrt(128)

    // per-wave P transpose slots, aliased into the sK region (16x72 x hi/lo)
    bf16_t (*pH)[72] = (bf16_t (*)[72])(smem + wave * 4608);
    bf16_t (*pL)[72] = (bf16_t (*)[72])(smem + wave * 4608 + 2304);

    // Q fragments, held in registers for the whole kernel
    bf16x8 qhF[2][4], qlF[2][4];
#pragma unroll
    for (int m = 0; m < 2; ++m) {
        long qoff = (tokB + q0 + m * 16 + n16) * 4096 + h * 128 + quad * 8;
#pragma unroll
        for (int f = 0; f < 4; ++f) {
            qhF[m][f] = *(const bf16x8*)&qhp[qoff + f * 32];
            qlF[m][f] = *(const bf16x8*)&qlp[qoff + f * 32];
        }
    }

    f32x4 o[2][8];
#pragma unroll
    for (int m = 0; m < 2; ++m)
#pragma unroll
        for (int dc = 0; dc < 8; ++dc) o[m][dc] = (f32x4){0.f, 0.f, 0.f, 0.f};
    float m_i[2][4], l_i[2][4];
#pragma unroll
    for (int m = 0; m < 2; ++m)
#pragma unroll
        for (int r = 0; r < 4; ++r) { m_i[m][r] = -1e30f; l_i[m][r] = 0.f; }

    const int nkb = 2 * qt + 2;
    for (int kb = 0; kb < nkb; ++kb) {
        // ---- stage K (64x128) and V^T (128x64), hi+lo, coalesced ----
        {
            const long keyTok = tokB + kb * 64;
#pragma unroll
            for (int i = 0; i < 4; ++i) {
                int idx = i * 256 + tid;
                int kr = idx >> 4, kc = (idx & 15) << 3;
                long g = (keyTok + kr) * 4096 + h * 128 + kc;
                *(bf16x8*)&sKh[kr][kc] = *(const bf16x8*)&khp[g];
                *(bf16x8*)&sKl[kr][kc] = *(const bf16x8*)&klp[g];
            }
#pragma unroll
            for (int i = 0; i < 4; ++i) {
                int idx = i * 256 + tid;
                int vr = idx >> 3, vc = (idx & 7) << 3;
                long g = (long)(bh * 128 + vr) * 2048 + kb * 64 + vc;
                *(bf16x8*)&sVh[vr][vc] = *(const bf16x8*)&vth[g];
                *(bf16x8*)&sVl[vr][vc] = *(const bf16x8*)&vtl[g];
            }
        }
        __syncthreads();

        // ---- scores: 2 x (16q x 64k), 3-pass split ----
        f32x4 s[2][4];
#pragma unroll
        for (int nt = 0; nt < 4; ++nt) {
            bf16x8 kh[4], kl[4];
#pragma unroll
            for (int f = 0; f < 4; ++f) {
                kh[f] = *(const bf16x8*)&sKh[nt * 16 + n16][f * 32 + quad * 8];
                kl[f] = *(const bf16x8*)&sKl[nt * 16 + n16][f * 32 + quad * 8];
            }
#pragma unroll
            for (int m = 0; m < 2; ++m) {
                f32x4 sc = (f32x4){0.f, 0.f, 0.f, 0.f};
#pragma unroll
                for (int f = 0; f < 4; ++f) {
                    sc = MFMA16(qhF[m][f], kh[f], sc);
                    sc = MFMA16(qhF[m][f], kl[f], sc);
                    sc = MFMA16(qlF[m][f], kh[f], sc);
                }
                int key = kb * 64 + nt * 16 + n16;
#pragma unroll
                for (int r = 0; r < 4; ++r) {
                    int qrow = q0 + m * 16 + quad * 4 + r;
                    s[m][nt][r] = (key <= qrow) ? sc[r] * scale : -1e30f;
                }
            }
        }

        // ---- online softmax (per m, per r; rows live in 16 contiguous lanes) ----
        float alpha[2][4];
#pragma unroll
        for (int m = 0; m < 2; ++m) {
#pragma unroll
            for (int r = 0; r < 4; ++r) {
                float mx = fmaxf(fmaxf(s[m][0][r], s[m][1][r]), fmaxf(s[m][2][r], s[m][3][r]));
#pragma unroll
                for (int off = 1; off < 16; off <<= 1) mx = fmaxf(mx, __shfl_xor(mx, off, 64));
                float mnew = fmaxf(m_i[m][r], mx);
                alpha[m][r] = expf(m_i[m][r] - mnew);
                m_i[m][r] = mnew;
                float sum = 0.f;
#pragma unroll
                for (int nt = 0; nt < 4; ++nt) {
                    float p = expf(s[m][nt][r] - mnew);
                    s[m][nt][r] = p;
                    sum += p;
                }
#pragma unroll
                for (int off = 1; off < 16; off <<= 1) sum += __shfl_xor(sum, off, 64);
                l_i[m][r] = l_i[m][r] * alpha[m][r] + sum;
            }
        }

        __syncthreads();   // all waves done reading sK before P aliases it

        // ---- per m: P -> LDS slot (C->A layout), PV accumulate ----
#pragma unroll
        for (int m = 0; m < 2; ++m) {
#pragma unroll
            for (int nt = 0; nt < 4; ++nt)
#pragma unroll
                for (int r = 0; r < 4; ++r) {
                    bf16_t hh2, ll2;
                    split_bf16(s[m][nt][r], hh2, ll2);
                    pH[quad * 4 + r][nt * 16 + n16] = hh2;
                    pL[quad * 4 + r][nt * 16 + n16] = ll2;
                }
            bf16x8 ph2[2], pl2[2];
#pragma unroll
            for (int kf = 0; kf < 2; ++kf) {
                ph2[kf] = *(const bf16x8*)&pH[n16][kf * 32 + quad * 8];
                pl2[kf] = *(const bf16x8*)&pL[n16][kf * 32 + quad * 8];
            }
#pragma unroll
            for (int dc = 0; dc < 8; ++dc) {
#pragma unroll
                for (int r = 0; r < 4; ++r) o[m][dc][r] *= alpha[m][r];
#pragma unroll
                for (int kf = 0; kf < 2; ++kf) {
                    bf16x8 vh = *(const bf16x8*)&sVh[dc * 16 + n16][kf * 32 + quad * 8];
                    bf16x8 vl = *(const bf16x8*)&sVl[dc * 16 + n16][kf * 32 + quad * 8];
                    o[m][dc] = MFMA16(ph2[kf], vh, o[m][dc]);
                    o[m][dc] = MFMA16(ph2[kf], vl, o[m][dc]);
                    o[m][dc] = MFMA16(pl2[kf], vh, o[m][dc]);
                }
            }
        }
        __syncthreads();   // PV + P reads done before next stage overwrites
    }

    // ---- normalize + write split ----
#pragma unroll
    for (int m = 0; m < 2; ++m)
#pragma unroll
        for (int r = 0; r < 4; ++r) {
            float invl = 1.0f / l_i[m][r];
            long row = tokB + q0 + m * 16 + quad * 4 + r;
#pragma unroll
            for (int dc = 0; dc < 8; ++dc) {
                bf16_t hh2, ll2;
                split_bf16(o[m][dc][r] * invl, hh2, ll2);
                ohi[row * 4096 + h * 128 + dc * 16 + n16] = hh2;
                olo[row * 4096 + h * 128 + dc * 16 + n16] = ll2;
            }
        }
}

// ---------------------------------------------------------------------------
// Launcher.  ws regions (64 MB each): W0 weights-split / vT, W1 q-split /
// Wo-split, W2 k-split / final fp32, OUT = d_out as v-split then attn-split
// scratch.  W3 only if ws_size >= 256 MB (pre-quantized activation cache).
// ---------------------------------------------------------------------------
extern "C" void kernel_launch(void* const* d_in, const int* in_sizes, int n_in,
                              void* d_out, int out_size, void* d_ws, size_t ws_size,
                              hipStream_t stream) {
    const float* x  = (const float*)d_in[0];
    const float* Wq = (const float*)d_in[1];
    const float* Wk = (const float*)d_in[2];
    const float* Wv = (const float*)d_in[3];
    const float* Wo = (const float*)d_in[4];
    const int* pos  = (const int*)d_in[5];
    const int* rid  = (const int*)d_in[6];

    const size_t MB = 1024ull * 1024ull;
    char* ws = (char*)d_ws;
    bf16_t* W0h = (bf16_t*)(ws);
    bf16_t* W0l = (bf16_t*)(ws + 32 * MB);
    bf16_t* W1h = (bf16_t*)(ws + 64 * MB);
    bf16_t* W1l = (bf16_t*)(ws + 96 * MB);
    bf16_t* W2h = (bf16_t*)(ws + 128 * MB);
    bf16_t* W2l = (bf16_t*)(ws + 160 * MB);
    bf16_t* OUh = (bf16_t*)d_out;
    bf16_t* OUl = (bf16_t*)((char*)d_out + 32 * MB);
    bf16_t* W3h = (bf16_t*)(ws + 192 * MB);
    bf16_t* W3l = (bf16_t*)(ws + 224 * MB);
    const bool fast = (ws_size >= 256 * MB);

    const int QG = 65536;

    // ---- q = xq @ Wq^T ----
    quant_split<<<QG, 256, 0, stream>>>(Wq, nullptr, nullptr, rid, 0, 0, W0h, W0l);
    if (fast) {
        quant_split<<<QG, 256, 0, stream>>>(x, nullptr, nullptr, rid, 0, 1, W3h, W3l);
        gemm_bt<0, 1, 1><<<1024, 256, 0, stream>>>(nullptr, W3h, W3l, rid, W0h, W0l, W1h, W1l, nullptr);
    } else {
        gemm_bt<1, 0, 1><<<1024, 256, 0, stream>>>(x, nullptr, nullptr, rid, W0h, W0l, W1h, W1l, nullptr);
    }
    // ---- k ----
    quant_split<<<QG, 256, 0, stream>>>(Wk, nullptr, nullptr, rid, 0, 0, W0h, W0l);
    if (fast)
        gemm_bt<0, 1, 1><<<1024, 256, 0, stream>>>(nullptr, W3h, W3l, rid, W0h, W0l, W2h, W2l, nullptr);
    else
        gemm_bt<1, 0, 1><<<1024, 256, 0, stream>>>(x, nullptr, nullptr, rid, W0h, W0l, W2h, W2l, nullptr);
    // ---- v (into d_out scratch) ----
    quant_split<<<QG, 256, 0, stream>>>(Wv, nullptr, nullptr, rid, 0, 0, W0h, W0l);
    if (fast)
        gemm_bt<0, 1, 1><<<1024, 256, 0, stream>>>(nullptr, W3h, W3l, rid, W0h, W0l, OUh, OUl, nullptr);
    else
        gemm_bt<1, 0, 1><<<1024, 256, 0, stream>>>(x, nullptr, nullptr, rid, W0h, W0l, OUh, OUl, nullptr);

    rope2<<<4096, 256, 0, stream>>>(W1h, W1l, W2h, W2l, pos);

    transpose_vt<<<dim3(64, 64), 256, 0, stream>>>((const ushort*)OUh, (const ushort*)OUl,
                                                   (ushort*)W0h, (ushort*)W0l);

    flash_attn2<<<dim3(16, 64), 256, 0, stream>>>(W1h, W1l, W2h, W2l, W0h, W0l, OUh, OUl);

    // ---- out = attnq @ Wo^T ----
    quant_split<<<QG, 256, 0, stream>>>(Wo, nullptr, nullptr, rid, 0, 0, W1h, W1l);
    if (fast) {
        quant_split<<<QG, 256, 0, stream>>>(nullptr, OUh, OUl, rid, 1, 1, W3h, W3l);
        gemm_bt<0, 1, 0><<<1024, 256, 0, stream>>>(nullptr, W3h, W3l, rid, W1h, W1l, nullptr, nullptr, (float*)d_out);
    } else {
        float* outf = (float*)W2h;   // k-split dead
        gemm_bt<1, 1, 0><<<1024, 256, 0, stream>>>(nullptr, OUh, OUl, rid, W1h, W1l, nullptr, nullptr, outf);
        hipMemcpyAsync(d_out, outf, 64 * MB, hipMemcpyDeviceToDevice, stream);
    }

    (void)in_sizes; (void)n_in; (void)out_size;
}